// Round 1
// baseline (2728.633 us; speedup 1.0000x reference)
//
#include <hip/hip_runtime.h>
#include <hip/hip_bf16.h>

#define THREADS 256

// ---------------- preprocessing ----------------

__global__ void count_deg_kernel(const int* __restrict__ col, int* __restrict__ deg, int E) {
    int e = blockIdx.x * blockDim.x + threadIdx.x;
    if (e < E) atomicAdd(&deg[col[e]], 1);
}

__global__ void dinv_kernel(const int* __restrict__ deg, float* __restrict__ dinv, int N) {
    int n = blockIdx.x * blockDim.x + threadIdx.x;
    if (n < N) {
        float d = (float)(deg[n] + 1);   // +1 self loop
        dinv[n] = 1.0f / sqrtf(d);
    }
}

// block-level sums for exclusive scan of deg[]
__global__ void scanA_kernel(const int* __restrict__ deg, int* __restrict__ blocksum, int N) {
    __shared__ int s[THREADS];
    int t = threadIdx.x;
    int idx = blockIdx.x * THREADS + t;
    s[t] = (idx < N) ? deg[idx] : 0;
    __syncthreads();
    for (int off = THREADS / 2; off > 0; off >>= 1) {
        if (t < off) s[t] += s[t + off];
        __syncthreads();
    }
    if (t == 0) blocksum[blockIdx.x] = s[0];
}

// single-block exclusive scan of blocksums (NB <= 512)
__global__ void scanB_kernel(const int* __restrict__ blocksum, int* __restrict__ blockoff, int NB) {
    __shared__ int s[512];
    int t = threadIdx.x;
    int v = (t < NB) ? blocksum[t] : 0;
    s[t] = v;
    __syncthreads();
    for (int off = 1; off < 512; off <<= 1) {
        int x = (t >= off) ? s[t - off] : 0;
        __syncthreads();
        s[t] += x;
        __syncthreads();
    }
    if (t < NB) blockoff[t] = s[t] - v;  // exclusive
}

__global__ void scanC_kernel(const int* __restrict__ deg, const int* __restrict__ blockoff,
                             int* __restrict__ rowptr, int N) {
    __shared__ int s[THREADS];
    int t = threadIdx.x;
    int idx = blockIdx.x * THREADS + t;
    int v = (idx < N) ? deg[idx] : 0;
    s[t] = v;
    __syncthreads();
    for (int off = 1; off < THREADS; off <<= 1) {
        int x = (t >= off) ? s[t - off] : 0;
        __syncthreads();
        s[t] += x;
        __syncthreads();
    }
    int base = blockoff[blockIdx.x];
    if (idx < N) {
        rowptr[idx] = base + s[t] - v;       // exclusive prefix
        if (idx == N - 1) rowptr[N] = base + s[t];
    }
}

// scatter edges into CSR (sorted by destination); payload packed (src, norm)
__global__ void fill_csr_kernel(const int* __restrict__ row, const int* __restrict__ col,
                                const int* __restrict__ rowptr, int* __restrict__ fill,
                                const float* __restrict__ dinv,
                                int2* __restrict__ srcw, int E) {
    int e = blockIdx.x * blockDim.x + threadIdx.x;
    if (e < E) {
        int s = row[e], d = col[e];
        int p = rowptr[d] + atomicAdd(&fill[d], 1);
        int2 sw;
        sw.x = s;
        sw.y = __float_as_int(dinv[s] * dinv[d]);
        srcw[p] = sw;
    }
}

// ---------------- dense layers ----------------

// h = x @ W0 + b0   (x: [N,128], W0: [128,32])  — 8 lanes/node, float4 each
__global__ __launch_bounds__(256) void lin0_kernel(const float* __restrict__ x,
        const float* __restrict__ W0, const float* __restrict__ b0,
        float* __restrict__ h, int N) {
    __shared__ float Ws[128 * 32];
    int t = threadIdx.x;
    for (int i = t; i < 128 * 32; i += 256) Ws[i] = W0[i];
    __syncthreads();
    int node = blockIdx.x * 32 + (t >> 3);
    int lane = t & 7;
    if (node >= N) return;
    float4 o = ((const float4*)b0)[lane];
    const float* xr = x + (size_t)node * 128;
    for (int k = 0; k < 128; ++k) {
        float a = xr[k];
        float4 w = *(const float4*)&Ws[k * 32 + lane * 4];
        o.x += a * w.x; o.y += a * w.y; o.z += a * w.z; o.w += a * w.w;
    }
    ((float4*)h)[(size_t)node * 8 + lane] = o;
}

// one SG layer: agg = D^-1/2 (A+I) D^-1/2 h ; hout = relu(agg @ W + b)
__global__ __launch_bounds__(256) void sg_layer_kernel(const float* __restrict__ hin,
        float* __restrict__ hout, const int* __restrict__ rowptr,
        const int2* __restrict__ srcw, const float* __restrict__ dinv,
        const float* __restrict__ W, const float* __restrict__ b, int N) {
    __shared__ float Ws[32 * 32];
    __shared__ float agg[32][33];   // 32 nodes/block, pad +1
    int t = threadIdx.x;
    for (int i = t; i < 32 * 32; i += 256) Ws[i] = W[i];
    int node = blockIdx.x * 32 + (t >> 3);
    int lane = t & 7;
    int ln = t >> 3;
    float4 acc = make_float4(0.f, 0.f, 0.f, 0.f);
    if (node < N) {
        const float4* hin4 = (const float4*)hin;
        float di = dinv[node];
        float wsl = di * di;                       // self-loop weight
        float4 hs = hin4[(size_t)node * 8 + lane];
        acc.x = wsl * hs.x; acc.y = wsl * hs.y; acc.z = wsl * hs.z; acc.w = wsl * hs.w;
        int e = rowptr[node], e1 = rowptr[node + 1];
        for (; e < e1; ++e) {
            int2 sw = srcw[e];
            float w = __int_as_float(sw.y);
            float4 hv = hin4[(size_t)sw.x * 8 + lane];
            acc.x += w * hv.x; acc.y += w * hv.y; acc.z += w * hv.z; acc.w += w * hv.w;
        }
    }
    agg[ln][lane * 4 + 0] = acc.x;
    agg[ln][lane * 4 + 1] = acc.y;
    agg[ln][lane * 4 + 2] = acc.z;
    agg[ln][lane * 4 + 3] = acc.w;
    __syncthreads();
    if (node < N) {
        float4 o = ((const float4*)b)[lane];
        for (int k = 0; k < 32; ++k) {
            float a = agg[ln][k];                   // broadcast across 8 lanes
            float4 w4 = *(const float4*)&Ws[k * 32 + lane * 4];
            o.x += a * w4.x; o.y += a * w4.y; o.z += a * w4.z; o.w += a * w4.w;
        }
        o.x = fmaxf(o.x, 0.f); o.y = fmaxf(o.y, 0.f);
        o.z = fmaxf(o.z, 0.f); o.w = fmaxf(o.w, 0.f);
        ((float4*)hout)[(size_t)node * 8 + lane] = o;
    }
}

// out = h @ W32 + b32  (h: [N,32], W32: [32,64]) — 16 lanes/node, float4 each
__global__ __launch_bounds__(256) void linout_kernel(const float* __restrict__ h,
        const float* __restrict__ W32, const float* __restrict__ b32,
        float* __restrict__ out, int N) {
    __shared__ float Ws[32 * 64];
    int t = threadIdx.x;
    for (int i = t; i < 32 * 64; i += 256) Ws[i] = W32[i];
    __syncthreads();
    int node = blockIdx.x * 16 + (t >> 4);
    int lane = t & 15;
    if (node >= N) return;
    float4 o = ((const float4*)b32)[lane];
    const float* hr = h + (size_t)node * 32;
    for (int k = 0; k < 32; ++k) {
        float a = hr[k];
        float4 w = *(const float4*)&Ws[k * 64 + lane * 4];
        o.x += a * w.x; o.y += a * w.y; o.z += a * w.z; o.w += a * w.w;
    }
    ((float4*)out)[(size_t)node * 16 + lane] = o;
}

// ---------------- launch ----------------

extern "C" void kernel_launch(void* const* d_in, const int* in_sizes, int n_in,
                              void* d_out, int out_size, void* d_ws, size_t ws_size,
                              hipStream_t stream) {
    const float* x     = (const float*)d_in[0];
    const float* W0    = (const float*)d_in[1];
    const float* b0    = (const float*)d_in[2];
    const float* Wsall = (const float*)d_in[3];
    const float* bsall = (const float*)d_in[4];
    const float* W32   = (const float*)d_in[5];
    const float* b32   = (const float*)d_in[6];
    const int*   ei    = (const int*)d_in[7];

    const int N   = in_sizes[0] / 128;
    const int E   = in_sizes[7] / 2;
    const int NSG = in_sizes[3] / (32 * 32);
    const int* erow = ei;       // sources
    const int* ecol = ei + E;   // destinations

    char* ws = (char*)d_ws;
    size_t off = 0;
    auto alloc = [&](size_t bytes) { size_t p = off; off += (bytes + 255) & ~(size_t)255; return p; };
    size_t degOff   = alloc((size_t)N * 4);
    size_t fillOff  = alloc((size_t)N * 4);
    size_t rpOff    = alloc((size_t)(N + 1) * 4);
    size_t bsumOff  = alloc(512 * 4);
    size_t boffOff  = alloc(512 * 4);
    size_t dinvOff  = alloc((size_t)N * 4);
    size_t srcwOff  = alloc((size_t)E * 8);
    size_t hAOff    = alloc((size_t)N * 32 * 4);
    size_t hBOff    = alloc((size_t)N * 32 * 4);

    int*   deg    = (int*)(ws + degOff);
    int*   fill   = (int*)(ws + fillOff);
    int*   rowptr = (int*)(ws + rpOff);
    int*   bsum   = (int*)(ws + bsumOff);
    int*   boff   = (int*)(ws + boffOff);
    float* dinv   = (float*)(ws + dinvOff);
    int2*  srcw   = (int2*)(ws + srcwOff);
    float* hA     = (float*)(ws + hAOff);
    float* hB     = (float*)(ws + hBOff);

    // zero deg + fill (contiguous region)
    hipMemsetAsync(ws + degOff, 0, fillOff + (size_t)N * 4 - degOff, stream);

    const int egrid = (E + THREADS - 1) / THREADS;
    const int ngrid = (N + THREADS - 1) / THREADS;   // also #blocks for scan (<=512)

    count_deg_kernel<<<egrid, THREADS, 0, stream>>>(ecol, deg, E);
    dinv_kernel<<<ngrid, THREADS, 0, stream>>>(deg, dinv, N);
    scanA_kernel<<<ngrid, THREADS, 0, stream>>>(deg, bsum, N);
    scanB_kernel<<<1, 512, 0, stream>>>(bsum, boff, ngrid);
    scanC_kernel<<<ngrid, THREADS, 0, stream>>>(deg, boff, rowptr, N);
    fill_csr_kernel<<<egrid, THREADS, 0, stream>>>(erow, ecol, rowptr, fill, dinv, srcw, E);

    lin0_kernel<<<(N + 31) / 32, 256, 0, stream>>>(x, W0, b0, hA, N);

    float* cur = hA;
    float* nxt = hB;
    for (int l = 0; l < NSG; ++l) {
        sg_layer_kernel<<<(N + 31) / 32, 256, 0, stream>>>(
            cur, nxt, rowptr, srcw, dinv, Wsall + (size_t)l * 32 * 32, bsall + (size_t)l * 32, N);
        float* tmp = cur; cur = nxt; nxt = tmp;
    }

    linout_kernel<<<(N + 15) / 16, 256, 0, stream>>>(cur, W32, b32, (float*)d_out, N);
}

// Round 3
// 2240.032 us; speedup vs baseline: 1.2181x; 1.2181x over previous
//
#include <hip/hip_runtime.h>
#include <hip/hip_bf16.h>

#define THREADS 256

// ---------------- preprocessing ----------------

__global__ void count_deg_kernel(const int* __restrict__ col, int* __restrict__ deg, int E) {
    int e = blockIdx.x * blockDim.x + threadIdx.x;
    if (e < E) atomicAdd(&deg[col[e]], 1);
}

__global__ void dinv_kernel(const int* __restrict__ deg, float* __restrict__ dinv, int N) {
    int n = blockIdx.x * blockDim.x + threadIdx.x;
    if (n < N) {
        float d = (float)(deg[n] + 1);   // +1 self loop
        dinv[n] = 1.0f / sqrtf(d);
    }
}

// block-level sums for exclusive scan of deg[]
__global__ void scanA_kernel(const int* __restrict__ deg, int* __restrict__ blocksum, int N) {
    __shared__ int s[THREADS];
    int t = threadIdx.x;
    int idx = blockIdx.x * THREADS + t;
    s[t] = (idx < N) ? deg[idx] : 0;
    __syncthreads();
    for (int off = THREADS / 2; off > 0; off >>= 1) {
        if (t < off) s[t] += s[t + off];
        __syncthreads();
    }
    if (t == 0) blocksum[blockIdx.x] = s[0];
}

// single-block exclusive scan of blocksums (NB <= 512)
__global__ void scanB_kernel(const int* __restrict__ blocksum, int* __restrict__ blockoff, int NB) {
    __shared__ int s[512];
    int t = threadIdx.x;
    int v = (t < NB) ? blocksum[t] : 0;
    s[t] = v;
    __syncthreads();
    for (int off = 1; off < 512; off <<= 1) {
        int x = (t >= off) ? s[t - off] : 0;
        __syncthreads();
        s[t] += x;
        __syncthreads();
    }
    if (t < NB) blockoff[t] = s[t] - v;  // exclusive
}

__global__ void scanC_kernel(const int* __restrict__ deg, const int* __restrict__ blockoff,
                             int* __restrict__ rowptr, int N) {
    __shared__ int s[THREADS];
    int t = threadIdx.x;
    int idx = blockIdx.x * THREADS + t;
    int v = (idx < N) ? deg[idx] : 0;
    s[t] = v;
    __syncthreads();
    for (int off = 1; off < THREADS; off <<= 1) {
        int x = (t >= off) ? s[t - off] : 0;
        __syncthreads();
        s[t] += x;
        __syncthreads();
    }
    int base = blockoff[blockIdx.x];
    if (idx < N) {
        rowptr[idx] = base + s[t] - v;       // exclusive prefix
        if (idx == N - 1) rowptr[N] = base + s[t];
    }
}

// scatter edges into CSR (sorted by destination); payload = src index only (4B)
__global__ void fill_csr_kernel(const int* __restrict__ row, const int* __restrict__ col,
                                const int* __restrict__ rowptr, int* __restrict__ fill,
                                int* __restrict__ srcs, int E) {
    int e = blockIdx.x * blockDim.x + threadIdx.x;
    if (e < E) {
        int s = row[e], d = col[e];
        int p = rowptr[d] + atomicAdd(&fill[d], 1);
        srcs[p] = s;
    }
}

// ---------------- dense layers ----------------

// g = dinv * (x @ W0 + b0)   (x: [N,128], W0: [128,32])  — 8 lanes/node, float4 each
__global__ __launch_bounds__(256) void lin0_kernel(const float* __restrict__ x,
        const float* __restrict__ W0, const float* __restrict__ b0,
        const float* __restrict__ dinv, float* __restrict__ g, int N) {
    __shared__ float Ws[128 * 32];
    int t = threadIdx.x;
    for (int i = t; i < 128 * 32; i += 256) Ws[i] = W0[i];
    __syncthreads();
    int node = blockIdx.x * 32 + (t >> 3);
    int lane = t & 7;
    if (node >= N) return;
    float4 o = ((const float4*)b0)[lane];
    const float* xr = x + (size_t)node * 128;
    for (int k = 0; k < 128; ++k) {
        float a = xr[k];
        float4 w = *(const float4*)&Ws[k * 32 + lane * 4];
        o.x += a * w.x; o.y += a * w.y; o.z += a * w.z; o.w += a * w.w;
    }
    float di = dinv[node];
    o.x *= di; o.y *= di; o.z *= di; o.w *= di;
    ((float4*)g)[(size_t)node * 8 + lane] = o;
}

// one SG layer on pre-scaled features g_in = dinv .* h_in:
//   acc  = sum_{src in N(dst)} g_in[src] + g_in[dst]        (self loop)
//   h    = relu(dinv[dst] * (acc @ W) + b)
//   out  = last ? h : dinv[dst] * h
__global__ __launch_bounds__(256) void sg_layer_kernel(const float* __restrict__ g_in,
        float* __restrict__ g_out, const int* __restrict__ rowptr,
        const int* __restrict__ srcs, const float* __restrict__ dinv,
        const float* __restrict__ W, const float* __restrict__ b, int N, int last) {
    __shared__ float Ws[32 * 32];
    __shared__ float agg[32][33];   // 32 nodes/block, pad +1
    int t = threadIdx.x;
    for (int i = t; i < 32 * 32; i += 256) Ws[i] = W[i];
    int node = blockIdx.x * 32 + (t >> 3);
    int lane = t & 7;
    int ln = t >> 3;
    float4 acc = make_float4(0.f, 0.f, 0.f, 0.f);
    if (node < N) {
        const float4* g4 = (const float4*)g_in;
        acc = g4[(size_t)node * 8 + lane];          // self-loop term g[node]
        int e = rowptr[node], e1 = rowptr[node + 1];
        // unrolled x4: batch index loads, then 4 outstanding gathers
        for (; e + 4 <= e1; e += 4) {
            int s0 = srcs[e], s1 = srcs[e + 1], s2 = srcs[e + 2], s3 = srcs[e + 3];
            float4 v0 = g4[(size_t)s0 * 8 + lane];
            float4 v1 = g4[(size_t)s1 * 8 + lane];
            float4 v2 = g4[(size_t)s2 * 8 + lane];
            float4 v3 = g4[(size_t)s3 * 8 + lane];
            acc.x += (v0.x + v1.x) + (v2.x + v3.x);
            acc.y += (v0.y + v1.y) + (v2.y + v3.y);
            acc.z += (v0.z + v1.z) + (v2.z + v3.z);
            acc.w += (v0.w + v1.w) + (v2.w + v3.w);
        }
        for (; e < e1; ++e) {
            float4 v = g4[(size_t)srcs[e] * 8 + lane];
            acc.x += v.x; acc.y += v.y; acc.z += v.z; acc.w += v.w;
        }
    }
    agg[ln][lane * 4 + 0] = acc.x;
    agg[ln][lane * 4 + 1] = acc.y;
    agg[ln][lane * 4 + 2] = acc.z;
    agg[ln][lane * 4 + 3] = acc.w;
    __syncthreads();
    if (node < N) {
        float4 m = make_float4(0.f, 0.f, 0.f, 0.f);
        for (int k = 0; k < 32; ++k) {
            float a = agg[ln][k];                   // broadcast across 8 lanes
            float4 w4 = *(const float4*)&Ws[k * 32 + lane * 4];
            m.x += a * w4.x; m.y += a * w4.y; m.z += a * w4.z; m.w += a * w4.w;
        }
        float di = dinv[node];
        float4 bb = ((const float4*)b)[lane];
        float4 o;
        o.x = fmaxf(fmaf(di, m.x, bb.x), 0.f);
        o.y = fmaxf(fmaf(di, m.y, bb.y), 0.f);
        o.z = fmaxf(fmaf(di, m.z, bb.z), 0.f);
        o.w = fmaxf(fmaf(di, m.w, bb.w), 0.f);
        if (!last) { o.x *= di; o.y *= di; o.z *= di; o.w *= di; }
        ((float4*)g_out)[(size_t)node * 8 + lane] = o;
    }
}

// out = h @ W32 + b32  (h: [N,32], W32: [32,64]) — 16 lanes/node, float4 each
__global__ __launch_bounds__(256) void linout_kernel(const float* __restrict__ h,
        const float* __restrict__ W32, const float* __restrict__ b32,
        float* __restrict__ out, int N) {
    __shared__ float Ws[32 * 64];
    int t = threadIdx.x;
    for (int i = t; i < 32 * 64; i += 256) Ws[i] = W32[i];
    __syncthreads();
    int node = blockIdx.x * 16 + (t >> 4);
    int lane = t & 15;
    if (node >= N) return;
    float4 o = ((const float4*)b32)[lane];
    const float* hr = h + (size_t)node * 32;
    for (int k = 0; k < 32; ++k) {
        float a = hr[k];
        float4 w = *(const float4*)&Ws[k * 64 + lane * 4];
        o.x += a * w.x; o.y += a * w.y; o.z += a * w.z; o.w += a * w.w;
    }
    ((float4*)out)[(size_t)node * 16 + lane] = o;
}

// ---------------- launch ----------------

extern "C" void kernel_launch(void* const* d_in, const int* in_sizes, int n_in,
                              void* d_out, int out_size, void* d_ws, size_t ws_size,
                              hipStream_t stream) {
    const float* x     = (const float*)d_in[0];
    const float* W0    = (const float*)d_in[1];
    const float* b0    = (const float*)d_in[2];
    const float* Wsall = (const float*)d_in[3];
    const float* bsall = (const float*)d_in[4];
    const float* W32   = (const float*)d_in[5];
    const float* b32   = (const float*)d_in[6];
    const int*   ei    = (const int*)d_in[7];

    const int N   = in_sizes[0] / 128;
    const int E   = in_sizes[7] / 2;
    const int NSG = in_sizes[3] / (32 * 32);
    const int* erow = ei;       // sources
    const int* ecol = ei + E;   // destinations

    char* ws = (char*)d_ws;
    size_t off = 0;
    auto alloc = [&](size_t bytes) { size_t p = off; off += (bytes + 255) & ~(size_t)255; return p; };
    size_t degOff   = alloc((size_t)N * 4);
    size_t fillOff  = alloc((size_t)N * 4);
    size_t rpOff    = alloc((size_t)(N + 1) * 4);
    size_t bsumOff  = alloc(512 * 4);
    size_t boffOff  = alloc(512 * 4);
    size_t dinvOff  = alloc((size_t)N * 4);
    size_t srcsOff  = alloc((size_t)E * 4);
    size_t hAOff    = alloc((size_t)N * 32 * 4);
    size_t hBOff    = alloc((size_t)N * 32 * 4);

    int*   deg    = (int*)(ws + degOff);
    int*   fill   = (int*)(ws + fillOff);
    int*   rowptr = (int*)(ws + rpOff);
    int*   bsum   = (int*)(ws + bsumOff);
    int*   boff   = (int*)(ws + boffOff);
    float* dinv   = (float*)(ws + dinvOff);
    int*   srcs   = (int*)(ws + srcsOff);
    float* hA     = (float*)(ws + hAOff);
    float* hB     = (float*)(ws + hBOff);

    // zero deg + fill (contiguous region)
    hipMemsetAsync(ws + degOff, 0, fillOff + (size_t)N * 4 - degOff, stream);

    const int egrid = (E + THREADS - 1) / THREADS;
    const int ngrid = (N + THREADS - 1) / THREADS;   // also #blocks for scan (<=512)

    count_deg_kernel<<<egrid, THREADS, 0, stream>>>(ecol, deg, E);
    dinv_kernel<<<ngrid, THREADS, 0, stream>>>(deg, dinv, N);
    scanA_kernel<<<ngrid, THREADS, 0, stream>>>(deg, bsum, N);
    scanB_kernel<<<1, 512, 0, stream>>>(bsum, boff, ngrid);
    scanC_kernel<<<ngrid, THREADS, 0, stream>>>(deg, boff, rowptr, N);
    fill_csr_kernel<<<egrid, THREADS, 0, stream>>>(erow, ecol, rowptr, fill, srcs, E);

    lin0_kernel<<<(N + 31) / 32, 256, 0, stream>>>(x, W0, b0, dinv, hA, N);

    float* cur = hA;
    float* nxt = hB;
    for (int l = 0; l < NSG; ++l) {
        sg_layer_kernel<<<(N + 31) / 32, 256, 0, stream>>>(
            cur, nxt, rowptr, srcs, dinv,
            Wsall + (size_t)l * 32 * 32, bsall + (size_t)l * 32, N, (l == NSG - 1) ? 1 : 0);
        float* tmp = cur; cur = nxt; nxt = tmp;
    }

    linout_kernel<<<(N + 15) / 16, 256, 0, stream>>>(cur, W32, b32, (float*)d_out, N);
}

// Round 4
// 2216.357 us; speedup vs baseline: 1.2311x; 1.0107x over previous
//
#include <hip/hip_runtime.h>
#include <hip/hip_bf16.h>

#define THREADS 256

// ---------------- preprocessing ----------------

// 4 edges/thread: int4 coalesced load + 4 independent atomic chains in flight
__global__ void count_deg_kernel(const int* __restrict__ col, int* __restrict__ deg, int E) {
    int i = (blockIdx.x * blockDim.x + threadIdx.x) * 4;
    if (i + 4 <= E) {
        int4 d4 = *(const int4*)(col + i);
        atomicAdd(&deg[d4.x], 1);
        atomicAdd(&deg[d4.y], 1);
        atomicAdd(&deg[d4.z], 1);
        atomicAdd(&deg[d4.w], 1);
    } else {
        for (int e = i; e < E; ++e) atomicAdd(&deg[col[e]], 1);
    }
}

__global__ void dinv_kernel(const int* __restrict__ deg, float* __restrict__ dinv, int N) {
    int n = blockIdx.x * blockDim.x + threadIdx.x;
    if (n < N) {
        float d = (float)(deg[n] + 1);   // +1 self loop
        dinv[n] = 1.0f / sqrtf(d);
    }
}

// block-level sums for exclusive scan of deg[]
__global__ void scanA_kernel(const int* __restrict__ deg, int* __restrict__ blocksum, int N) {
    __shared__ int s[THREADS];
    int t = threadIdx.x;
    int idx = blockIdx.x * THREADS + t;
    s[t] = (idx < N) ? deg[idx] : 0;
    __syncthreads();
    for (int off = THREADS / 2; off > 0; off >>= 1) {
        if (t < off) s[t] += s[t + off];
        __syncthreads();
    }
    if (t == 0) blocksum[blockIdx.x] = s[0];
}

// single-block exclusive scan of blocksums (NB <= 512)
__global__ void scanB_kernel(const int* __restrict__ blocksum, int* __restrict__ blockoff, int NB) {
    __shared__ int s[512];
    int t = threadIdx.x;
    int v = (t < NB) ? blocksum[t] : 0;
    s[t] = v;
    __syncthreads();
    for (int off = 1; off < 512; off <<= 1) {
        int x = (t >= off) ? s[t - off] : 0;
        __syncthreads();
        s[t] += x;
        __syncthreads();
    }
    if (t < NB) blockoff[t] = s[t] - v;  // exclusive
}

__global__ void scanC_kernel(const int* __restrict__ deg, const int* __restrict__ blockoff,
                             int* __restrict__ rowptr, int N) {
    __shared__ int s[THREADS];
    int t = threadIdx.x;
    int idx = blockIdx.x * THREADS + t;
    int v = (idx < N) ? deg[idx] : 0;
    s[t] = v;
    __syncthreads();
    for (int off = 1; off < THREADS; off <<= 1) {
        int x = (t >= off) ? s[t - off] : 0;
        __syncthreads();
        s[t] += x;
        __syncthreads();
    }
    int base = blockoff[blockIdx.x];
    if (idx < N) {
        rowptr[idx] = base + s[t] - v;       // exclusive prefix
        if (idx == N - 1) rowptr[N] = base + s[t];
    }
}

// scatter edges into CSR (sorted by destination); 4 edges/thread for ILP
__global__ void fill_csr_kernel(const int* __restrict__ row, const int* __restrict__ col,
                                const int* __restrict__ rowptr, int* __restrict__ fill,
                                int* __restrict__ srcs, int E) {
    int i = (blockIdx.x * blockDim.x + threadIdx.x) * 4;
    if (i + 4 <= E) {
        int4 s4 = *(const int4*)(row + i);
        int4 d4 = *(const int4*)(col + i);
        int r0 = rowptr[d4.x], r1 = rowptr[d4.y], r2 = rowptr[d4.z], r3 = rowptr[d4.w];
        int p0 = r0 + atomicAdd(&fill[d4.x], 1);
        int p1 = r1 + atomicAdd(&fill[d4.y], 1);
        int p2 = r2 + atomicAdd(&fill[d4.z], 1);
        int p3 = r3 + atomicAdd(&fill[d4.w], 1);
        srcs[p0] = s4.x; srcs[p1] = s4.y; srcs[p2] = s4.z; srcs[p3] = s4.w;
    } else {
        for (int e = i; e < E; ++e) {
            int s = row[e], d = col[e];
            int p = rowptr[d] + atomicAdd(&fill[d], 1);
            srcs[p] = s;
        }
    }
}

// ---------------- dense layers ----------------

// g = dinv * (x @ W0 + b0)   (x: [N,128], W0: [128,32])  — 8 lanes/node, float4 each
__global__ __launch_bounds__(256) void lin0_kernel(const float* __restrict__ x,
        const float* __restrict__ W0, const float* __restrict__ b0,
        const float* __restrict__ dinv, float* __restrict__ g, int N) {
    __shared__ float Ws[128 * 32];
    int t = threadIdx.x;
    for (int i = t; i < 128 * 32; i += 256) Ws[i] = W0[i];
    __syncthreads();
    int node = blockIdx.x * 32 + (t >> 3);
    int lane = t & 7;
    if (node >= N) return;
    float4 o = ((const float4*)b0)[lane];
    const float* xr = x + (size_t)node * 128;
    for (int k = 0; k < 128; ++k) {
        float a = xr[k];
        float4 w = *(const float4*)&Ws[k * 32 + lane * 4];
        o.x += a * w.x; o.y += a * w.y; o.z += a * w.z; o.w += a * w.w;
    }
    float di = dinv[node];
    o.x *= di; o.y *= di; o.z *= di; o.w *= di;
    ((float4*)g)[(size_t)node * 8 + lane] = o;
}

// one SG layer on pre-scaled features g_in = dinv .* h_in:
//   acc  = sum_{src in N(dst)} g_in[src] + g_in[dst]        (self loop)
//   h    = relu(dinv[dst] * (acc @ W) + b)
//   out  = last ? h : dinv[dst] * h
// 8 lanes/node; gather pipeline 8 rows deep per group (64 rows/wave in flight).
__global__ __launch_bounds__(256) void sg_layer_kernel(const float* __restrict__ g_in,
        float* __restrict__ g_out, const int* __restrict__ rowptr,
        const int* __restrict__ srcs, const float* __restrict__ dinv,
        const float* __restrict__ W, const float* __restrict__ b, int N, int last) {
    __shared__ float Ws[32 * 32];
    __shared__ float agg[32][33];   // 32 nodes/block, pad +1
    int t = threadIdx.x;
    for (int i = t; i < 32 * 32; i += 256) Ws[i] = W[i];
    int node = blockIdx.x * 32 + (t >> 3);
    int lane = t & 7;
    int ln = t >> 3;
    float4 acc = make_float4(0.f, 0.f, 0.f, 0.f);
    if (node < N) {
        const float4* g4 = (const float4*)g_in;
        acc = g4[(size_t)node * 8 + lane];          // self-loop term g[node]
        int e = rowptr[node], e1 = rowptr[node + 1];
        for (; e + 8 <= e1; e += 8) {
            int s0 = srcs[e],     s1 = srcs[e + 1], s2 = srcs[e + 2], s3 = srcs[e + 3];
            int s4 = srcs[e + 4], s5 = srcs[e + 5], s6 = srcs[e + 6], s7 = srcs[e + 7];
            float4 v0 = g4[(size_t)s0 * 8 + lane];
            float4 v1 = g4[(size_t)s1 * 8 + lane];
            float4 v2 = g4[(size_t)s2 * 8 + lane];
            float4 v3 = g4[(size_t)s3 * 8 + lane];
            float4 v4 = g4[(size_t)s4 * 8 + lane];
            float4 v5 = g4[(size_t)s5 * 8 + lane];
            float4 v6 = g4[(size_t)s6 * 8 + lane];
            float4 v7 = g4[(size_t)s7 * 8 + lane];
            acc.x += ((v0.x + v1.x) + (v2.x + v3.x)) + ((v4.x + v5.x) + (v6.x + v7.x));
            acc.y += ((v0.y + v1.y) + (v2.y + v3.y)) + ((v4.y + v5.y) + (v6.y + v7.y));
            acc.z += ((v0.z + v1.z) + (v2.z + v3.z)) + ((v4.z + v5.z) + (v6.z + v7.z));
            acc.w += ((v0.w + v1.w) + (v2.w + v3.w)) + ((v4.w + v5.w) + (v6.w + v7.w));
        }
        for (; e + 4 <= e1; e += 4) {
            int s0 = srcs[e], s1 = srcs[e + 1], s2 = srcs[e + 2], s3 = srcs[e + 3];
            float4 v0 = g4[(size_t)s0 * 8 + lane];
            float4 v1 = g4[(size_t)s1 * 8 + lane];
            float4 v2 = g4[(size_t)s2 * 8 + lane];
            float4 v3 = g4[(size_t)s3 * 8 + lane];
            acc.x += (v0.x + v1.x) + (v2.x + v3.x);
            acc.y += (v0.y + v1.y) + (v2.y + v3.y);
            acc.z += (v0.z + v1.z) + (v2.z + v3.z);
            acc.w += (v0.w + v1.w) + (v2.w + v3.w);
        }
        for (; e < e1; ++e) {
            float4 v = g4[(size_t)srcs[e] * 8 + lane];
            acc.x += v.x; acc.y += v.y; acc.z += v.z; acc.w += v.w;
        }
    }
    agg[ln][lane * 4 + 0] = acc.x;
    agg[ln][lane * 4 + 1] = acc.y;
    agg[ln][lane * 4 + 2] = acc.z;
    agg[ln][lane * 4 + 3] = acc.w;
    __syncthreads();
    if (node < N) {
        float4 m = make_float4(0.f, 0.f, 0.f, 0.f);
        for (int k = 0; k < 32; ++k) {
            float a = agg[ln][k];                   // broadcast across 8 lanes
            float4 w4 = *(const float4*)&Ws[k * 32 + lane * 4];
            m.x += a * w4.x; m.y += a * w4.y; m.z += a * w4.z; m.w += a * w4.w;
        }
        float di = dinv[node];
        float4 bb = ((const float4*)b)[lane];
        float4 o;
        o.x = fmaxf(fmaf(di, m.x, bb.x), 0.f);
        o.y = fmaxf(fmaf(di, m.y, bb.y), 0.f);
        o.z = fmaxf(fmaf(di, m.z, bb.z), 0.f);
        o.w = fmaxf(fmaf(di, m.w, bb.w), 0.f);
        if (!last) { o.x *= di; o.y *= di; o.z *= di; o.w *= di; }
        ((float4*)g_out)[(size_t)node * 8 + lane] = o;
    }
}

// out = h @ W32 + b32  (h: [N,32], W32: [32,64]) — 16 lanes/node, float4 each
__global__ __launch_bounds__(256) void linout_kernel(const float* __restrict__ h,
        const float* __restrict__ W32, const float* __restrict__ b32,
        float* __restrict__ out, int N) {
    __shared__ float Ws[32 * 64];
    int t = threadIdx.x;
    for (int i = t; i < 32 * 64; i += 256) Ws[i] = W32[i];
    __syncthreads();
    int node = blockIdx.x * 16 + (t >> 4);
    int lane = t & 15;
    if (node >= N) return;
    float4 o = ((const float4*)b32)[lane];
    const float* hr = h + (size_t)node * 32;
    for (int k = 0; k < 32; ++k) {
        float a = hr[k];
        float4 w = *(const float4*)&Ws[k * 64 + lane * 4];
        o.x += a * w.x; o.y += a * w.y; o.z += a * w.z; o.w += a * w.w;
    }
    ((float4*)out)[(size_t)node * 16 + lane] = o;
}

// ---------------- launch ----------------

extern "C" void kernel_launch(void* const* d_in, const int* in_sizes, int n_in,
                              void* d_out, int out_size, void* d_ws, size_t ws_size,
                              hipStream_t stream) {
    const float* x     = (const float*)d_in[0];
    const float* W0    = (const float*)d_in[1];
    const float* b0    = (const float*)d_in[2];
    const float* Wsall = (const float*)d_in[3];
    const float* bsall = (const float*)d_in[4];
    const float* W32   = (const float*)d_in[5];
    const float* b32   = (const float*)d_in[6];
    const int*   ei    = (const int*)d_in[7];

    const int N   = in_sizes[0] / 128;
    const int E   = in_sizes[7] / 2;
    const int NSG = in_sizes[3] / (32 * 32);
    const int* erow = ei;       // sources
    const int* ecol = ei + E;   // destinations

    char* ws = (char*)d_ws;
    size_t off = 0;
    auto alloc = [&](size_t bytes) { size_t p = off; off += (bytes + 255) & ~(size_t)255; return p; };
    size_t degOff   = alloc((size_t)N * 4);
    size_t fillOff  = alloc((size_t)N * 4);
    size_t rpOff    = alloc((size_t)(N + 1) * 4);
    size_t bsumOff  = alloc(512 * 4);
    size_t boffOff  = alloc(512 * 4);
    size_t dinvOff  = alloc((size_t)N * 4);
    size_t srcsOff  = alloc((size_t)E * 4);
    size_t hAOff    = alloc((size_t)N * 32 * 4);
    size_t hBOff    = alloc((size_t)N * 32 * 4);

    int*   deg    = (int*)(ws + degOff);
    int*   fill   = (int*)(ws + fillOff);
    int*   rowptr = (int*)(ws + rpOff);
    int*   bsum   = (int*)(ws + bsumOff);
    int*   boff   = (int*)(ws + boffOff);
    float* dinv   = (float*)(ws + dinvOff);
    int*   srcs   = (int*)(ws + srcsOff);
    float* hA     = (float*)(ws + hAOff);
    float* hB     = (float*)(ws + hBOff);

    // zero deg + fill (contiguous region)
    hipMemsetAsync(ws + degOff, 0, fillOff + (size_t)N * 4 - degOff, stream);

    const int e4grid = (E / 4 + THREADS - 1) / THREADS;   // 4 edges per thread
    const int ngrid  = (N + THREADS - 1) / THREADS;       // also #blocks for scan (<=512)

    count_deg_kernel<<<e4grid, THREADS, 0, stream>>>(ecol, deg, E);
    dinv_kernel<<<ngrid, THREADS, 0, stream>>>(deg, dinv, N);
    scanA_kernel<<<ngrid, THREADS, 0, stream>>>(deg, bsum, N);
    scanB_kernel<<<1, 512, 0, stream>>>(bsum, boff, ngrid);
    scanC_kernel<<<ngrid, THREADS, 0, stream>>>(deg, boff, rowptr, N);
    fill_csr_kernel<<<e4grid, THREADS, 0, stream>>>(erow, ecol, rowptr, fill, srcs, E);

    lin0_kernel<<<(N + 31) / 32, 256, 0, stream>>>(x, W0, b0, dinv, hA, N);

    float* cur = hA;
    float* nxt = hB;
    for (int l = 0; l < NSG; ++l) {
        sg_layer_kernel<<<(N + 31) / 32, 256, 0, stream>>>(
            cur, nxt, rowptr, srcs, dinv,
            Wsall + (size_t)l * 32 * 32, bsall + (size_t)l * 32, N, (l == NSG - 1) ? 1 : 0);
        float* tmp = cur; cur = nxt; nxt = tmp;
    }

    linout_kernel<<<(N + 15) / 16, 256, 0, stream>>>(cur, W32, b32, (float*)d_out, N);
}

// Round 5
// 1883.676 us; speedup vs baseline: 1.4486x; 1.1766x over previous
//
#include <hip/hip_runtime.h>
#include <hip/hip_bf16.h>

#define THREADS 256

typedef _Float16 f16;
typedef f16 f16x8 __attribute__((ext_vector_type(8)));
typedef f16 f16x4 __attribute__((ext_vector_type(4)));

// ---------------- preprocessing ----------------

__global__ void count_deg_kernel(const int* __restrict__ col, int* __restrict__ deg, int E) {
    int e = blockIdx.x * blockDim.x + threadIdx.x;
    if (e < E) atomicAdd(&deg[col[e]], 1);
}

__global__ void dinv_kernel(const int* __restrict__ deg, float* __restrict__ dinv, int N) {
    int n = blockIdx.x * blockDim.x + threadIdx.x;
    if (n < N) {
        float d = (float)(deg[n] + 1);   // +1 self loop
        dinv[n] = 1.0f / sqrtf(d);
    }
}

__global__ void scanA_kernel(const int* __restrict__ deg, int* __restrict__ blocksum, int N) {
    __shared__ int s[THREADS];
    int t = threadIdx.x;
    int idx = blockIdx.x * THREADS + t;
    s[t] = (idx < N) ? deg[idx] : 0;
    __syncthreads();
    for (int off = THREADS / 2; off > 0; off >>= 1) {
        if (t < off) s[t] += s[t + off];
        __syncthreads();
    }
    if (t == 0) blocksum[blockIdx.x] = s[0];
}

__global__ void scanB_kernel(const int* __restrict__ blocksum, int* __restrict__ blockoff, int NB) {
    __shared__ int s[512];
    int t = threadIdx.x;
    int v = (t < NB) ? blocksum[t] : 0;
    s[t] = v;
    __syncthreads();
    for (int off = 1; off < 512; off <<= 1) {
        int x = (t >= off) ? s[t - off] : 0;
        __syncthreads();
        s[t] += x;
        __syncthreads();
    }
    if (t < NB) blockoff[t] = s[t] - v;  // exclusive
}

__global__ void scanC_kernel(const int* __restrict__ deg, const int* __restrict__ blockoff,
                             int* __restrict__ rowptr, int N) {
    __shared__ int s[THREADS];
    int t = threadIdx.x;
    int idx = blockIdx.x * THREADS + t;
    int v = (idx < N) ? deg[idx] : 0;
    s[t] = v;
    __syncthreads();
    for (int off = 1; off < THREADS; off <<= 1) {
        int x = (t >= off) ? s[t - off] : 0;
        __syncthreads();
        s[t] += x;
        __syncthreads();
    }
    int base = blockoff[blockIdx.x];
    if (idx < N) {
        rowptr[idx] = base + s[t] - v;       // exclusive prefix
        if (idx == N - 1) rowptr[N] = base + s[t];
    }
}

// scatter edges into CSR (sorted by destination); 1 edge/thread (r4's 4/thread regressed)
__global__ void fill_csr_kernel(const int* __restrict__ row, const int* __restrict__ col,
                                const int* __restrict__ rowptr, int* __restrict__ fill,
                                int* __restrict__ srcs, int E) {
    int e = blockIdx.x * blockDim.x + threadIdx.x;
    if (e < E) {
        int s = row[e], d = col[e];
        int p = rowptr[d] + atomicAdd(&fill[d], 1);
        srcs[p] = s;
    }
}

// ---------------- dense layers ----------------

// g16 = (f16)(dinv * (x @ W0 + b0))   — 8 lanes/node, 4 ch each
__global__ __launch_bounds__(256) void lin0_kernel(const float* __restrict__ x,
        const float* __restrict__ W0, const float* __restrict__ b0,
        const float* __restrict__ dinv, f16* __restrict__ g, int N) {
    __shared__ float Ws[128 * 32];
    int t = threadIdx.x;
    for (int i = t; i < 128 * 32; i += 256) Ws[i] = W0[i];
    __syncthreads();
    int node = blockIdx.x * 32 + (t >> 3);
    int lane = t & 7;
    if (node >= N) return;
    float4 o = ((const float4*)b0)[lane];
    const float* xr = x + (size_t)node * 128;
    for (int k = 0; k < 128; ++k) {
        float a = xr[k];
        float4 w = *(const float4*)&Ws[k * 32 + lane * 4];
        o.x += a * w.x; o.y += a * w.y; o.z += a * w.z; o.w += a * w.w;
    }
    float di = dinv[node];
    f16x4 st;
    st.x = (f16)(o.x * di); st.y = (f16)(o.y * di);
    st.z = (f16)(o.z * di); st.w = (f16)(o.w * di);
    ((f16x4*)g)[(size_t)node * 8 + lane] = st;
}

// SG layer on fp16 pre-scaled features g_in = s_l * dinv .* h_l:
//   A    = sum_{src} g_in[src] + g_in[node]
//   o    = relu(dinv * (A @ W) + s_l * b)      ( = s_l * h_{l+1} )
//   non-last: g_out16 = (f16)(2 * dinv * o)    ( s_{l+1} = 2 s_l )
//   last:     h_out32 = o * 2^-30
// 4 lanes/node (16B fp16 gathers), 64 nodes/block, unroll x8.
__global__ __launch_bounds__(256) void sg_layer_kernel(const f16* __restrict__ g_in,
        f16* __restrict__ g_out16, float* __restrict__ h_out32,
        const int* __restrict__ rowptr, const int* __restrict__ srcs,
        const float* __restrict__ dinv, const float* __restrict__ W,
        const float* __restrict__ b, int N, float bscale, int last) {
    __shared__ float Ws[32 * 32];
    __shared__ float agg[64][33];
    int t = threadIdx.x;
    for (int i = t; i < 32 * 32; i += 256) Ws[i] = W[i];
    int node = blockIdx.x * 64 + (t >> 2);
    int lane = t & 3;
    int ln = t >> 2;
    float o0=0.f,o1=0.f,o2=0.f,o3=0.f,o4=0.f,o5=0.f,o6=0.f,o7=0.f;
    if (node < N) {
        const f16x8* g8 = (const f16x8*)g_in;
        f16x8 sv = g8[(size_t)node * 4 + lane];      // self-loop term
        o0=(float)sv[0]; o1=(float)sv[1]; o2=(float)sv[2]; o3=(float)sv[3];
        o4=(float)sv[4]; o5=(float)sv[5]; o6=(float)sv[6]; o7=(float)sv[7];
        int e = rowptr[node], e1 = rowptr[node + 1];
        for (; e + 8 <= e1; e += 8) {
            int s0 = srcs[e],     s1 = srcs[e + 1], s2 = srcs[e + 2], s3 = srcs[e + 3];
            int s4 = srcs[e + 4], s5 = srcs[e + 5], s6 = srcs[e + 6], s7 = srcs[e + 7];
            f16x8 v0 = g8[(size_t)s0 * 4 + lane];
            f16x8 v1 = g8[(size_t)s1 * 4 + lane];
            f16x8 v2 = g8[(size_t)s2 * 4 + lane];
            f16x8 v3 = g8[(size_t)s3 * 4 + lane];
            f16x8 v4 = g8[(size_t)s4 * 4 + lane];
            f16x8 v5 = g8[(size_t)s5 * 4 + lane];
            f16x8 v6 = g8[(size_t)s6 * 4 + lane];
            f16x8 v7 = g8[(size_t)s7 * 4 + lane];
            o0 += ((float)v0[0]+(float)v1[0])+((float)v2[0]+(float)v3[0])
                + ((float)v4[0]+(float)v5[0])+((float)v6[0]+(float)v7[0]);
            o1 += ((float)v0[1]+(float)v1[1])+((float)v2[1]+(float)v3[1])
                + ((float)v4[1]+(float)v5[1])+((float)v6[1]+(float)v7[1]);
            o2 += ((float)v0[2]+(float)v1[2])+((float)v2[2]+(float)v3[2])
                + ((float)v4[2]+(float)v5[2])+((float)v6[2]+(float)v7[2]);
            o3 += ((float)v0[3]+(float)v1[3])+((float)v2[3]+(float)v3[3])
                + ((float)v4[3]+(float)v5[3])+((float)v6[3]+(float)v7[3]);
            o4 += ((float)v0[4]+(float)v1[4])+((float)v2[4]+(float)v3[4])
                + ((float)v4[4]+(float)v5[4])+((float)v6[4]+(float)v7[4]);
            o5 += ((float)v0[5]+(float)v1[5])+((float)v2[5]+(float)v3[5])
                + ((float)v4[5]+(float)v5[5])+((float)v6[5]+(float)v7[5]);
            o6 += ((float)v0[6]+(float)v1[6])+((float)v2[6]+(float)v3[6])
                + ((float)v4[6]+(float)v5[6])+((float)v6[6]+(float)v7[6]);
            o7 += ((float)v0[7]+(float)v1[7])+((float)v2[7]+(float)v3[7])
                + ((float)v4[7]+(float)v5[7])+((float)v6[7]+(float)v7[7]);
        }
        for (; e < e1; ++e) {
            f16x8 v = g8[(size_t)srcs[e] * 4 + lane];
            o0 += (float)v[0]; o1 += (float)v[1]; o2 += (float)v[2]; o3 += (float)v[3];
            o4 += (float)v[4]; o5 += (float)v[5]; o6 += (float)v[6]; o7 += (float)v[7];
        }
    }
    int c = lane * 8;
    agg[ln][c + 0] = o0; agg[ln][c + 1] = o1; agg[ln][c + 2] = o2; agg[ln][c + 3] = o3;
    agg[ln][c + 4] = o4; agg[ln][c + 5] = o5; agg[ln][c + 6] = o6; agg[ln][c + 7] = o7;
    __syncthreads();
    if (node < N) {
        float4 ma = make_float4(0.f, 0.f, 0.f, 0.f);
        float4 mb = make_float4(0.f, 0.f, 0.f, 0.f);
        for (int k = 0; k < 32; ++k) {
            float a = agg[ln][k];
            float4 wa = *(const float4*)&Ws[k * 32 + c];
            float4 wb = *(const float4*)&Ws[k * 32 + c + 4];
            ma.x += a * wa.x; ma.y += a * wa.y; ma.z += a * wa.z; ma.w += a * wa.w;
            mb.x += a * wb.x; mb.y += a * wb.y; mb.z += a * wb.z; mb.w += a * wb.w;
        }
        float di = dinv[node];
        float4 ba = *(const float4*)&b[c];
        float4 bb = *(const float4*)&b[c + 4];
        float r0 = fmaxf(fmaf(di, ma.x, bscale * ba.x), 0.f);
        float r1 = fmaxf(fmaf(di, ma.y, bscale * ba.y), 0.f);
        float r2 = fmaxf(fmaf(di, ma.z, bscale * ba.z), 0.f);
        float r3 = fmaxf(fmaf(di, ma.w, bscale * ba.w), 0.f);
        float r4 = fmaxf(fmaf(di, mb.x, bscale * bb.x), 0.f);
        float r5 = fmaxf(fmaf(di, mb.y, bscale * bb.y), 0.f);
        float r6 = fmaxf(fmaf(di, mb.z, bscale * bb.z), 0.f);
        float r7 = fmaxf(fmaf(di, mb.w, bscale * bb.w), 0.f);
        if (!last) {
            float sc = 2.0f * di;                     // s_{l+1} = 2 s_l, pre-scale by dinv
            f16x8 st;
            st[0]=(f16)(r0*sc); st[1]=(f16)(r1*sc); st[2]=(f16)(r2*sc); st[3]=(f16)(r3*sc);
            st[4]=(f16)(r4*sc); st[5]=(f16)(r5*sc); st[6]=(f16)(r6*sc); st[7]=(f16)(r7*sc);
            ((f16x8*)g_out16)[(size_t)node * 4 + lane] = st;
        } else {
            const float inv = 1.0f / 1073741824.0f;   // 2^-30 (s_30 = 2^30)
            float4 wa = make_float4(r0*inv, r1*inv, r2*inv, r3*inv);
            float4 wb = make_float4(r4*inv, r5*inv, r6*inv, r7*inv);
            float4* hp = (float4*)(h_out32 + (size_t)node * 32 + c);
            hp[0] = wa; hp[1] = wb;
        }
    }
}

// out = h @ W32 + b32  (h: [N,32] fp32, W32: [32,64]) — 16 lanes/node
__global__ __launch_bounds__(256) void linout_kernel(const float* __restrict__ h,
        const float* __restrict__ W32, const float* __restrict__ b32,
        float* __restrict__ out, int N) {
    __shared__ float Ws[32 * 64];
    int t = threadIdx.x;
    for (int i = t; i < 32 * 64; i += 256) Ws[i] = W32[i];
    __syncthreads();
    int node = blockIdx.x * 16 + (t >> 4);
    int lane = t & 15;
    if (node >= N) return;
    float4 o = ((const float4*)b32)[lane];
    const float* hr = h + (size_t)node * 32;
    for (int k = 0; k < 32; ++k) {
        float a = hr[k];
        float4 w = *(const float4*)&Ws[k * 64 + lane * 4];
        o.x += a * w.x; o.y += a * w.y; o.z += a * w.z; o.w += a * w.w;
    }
    ((float4*)out)[(size_t)node * 16 + lane] = o;
}

// ---------------- launch ----------------

extern "C" void kernel_launch(void* const* d_in, const int* in_sizes, int n_in,
                              void* d_out, int out_size, void* d_ws, size_t ws_size,
                              hipStream_t stream) {
    const float* x     = (const float*)d_in[0];
    const float* W0    = (const float*)d_in[1];
    const float* b0    = (const float*)d_in[2];
    const float* Wsall = (const float*)d_in[3];
    const float* bsall = (const float*)d_in[4];
    const float* W32   = (const float*)d_in[5];
    const float* b32   = (const float*)d_in[6];
    const int*   ei    = (const int*)d_in[7];

    const int N   = in_sizes[0] / 128;
    const int E   = in_sizes[7] / 2;
    const int NSG = in_sizes[3] / (32 * 32);
    const int* erow = ei;       // sources
    const int* ecol = ei + E;   // destinations

    char* ws = (char*)d_ws;
    size_t off = 0;
    auto alloc = [&](size_t bytes) { size_t p = off; off += (bytes + 255) & ~(size_t)255; return p; };
    size_t degOff   = alloc((size_t)N * 4);
    size_t fillOff  = alloc((size_t)N * 4);
    size_t rpOff    = alloc((size_t)(N + 1) * 4);
    size_t bsumOff  = alloc(512 * 4);
    size_t boffOff  = alloc(512 * 4);
    size_t dinvOff  = alloc((size_t)N * 4);
    size_t srcsOff  = alloc((size_t)E * 4);
    size_t gAOff    = alloc((size_t)N * 32 * 2);   // fp16 features A
    size_t gBOff    = alloc((size_t)N * 32 * 2);   // fp16 features B
    size_t hFOff    = alloc((size_t)N * 32 * 4);   // fp32 final hidden

    int*   deg    = (int*)(ws + degOff);
    int*   fill   = (int*)(ws + fillOff);
    int*   rowptr = (int*)(ws + rpOff);
    int*   bsum   = (int*)(ws + bsumOff);
    int*   boff   = (int*)(ws + boffOff);
    float* dinv   = (float*)(ws + dinvOff);
    int*   srcs   = (int*)(ws + srcsOff);
    f16*   gA     = (f16*)(ws + gAOff);
    f16*   gB     = (f16*)(ws + gBOff);
    float* hF     = (float*)(ws + hFOff);

    hipMemsetAsync(ws + degOff, 0, fillOff + (size_t)N * 4 - degOff, stream);

    const int egrid = (E + THREADS - 1) / THREADS;
    const int ngrid = (N + THREADS - 1) / THREADS;

    count_deg_kernel<<<egrid, THREADS, 0, stream>>>(ecol, deg, E);
    dinv_kernel<<<ngrid, THREADS, 0, stream>>>(deg, dinv, N);
    scanA_kernel<<<ngrid, THREADS, 0, stream>>>(deg, bsum, N);
    scanB_kernel<<<1, 512, 0, stream>>>(bsum, boff, ngrid);
    scanC_kernel<<<ngrid, THREADS, 0, stream>>>(deg, boff, rowptr, N);
    fill_csr_kernel<<<egrid, THREADS, 0, stream>>>(erow, ecol, rowptr, fill, srcs, E);

    lin0_kernel<<<(N + 31) / 32, 256, 0, stream>>>(x, W0, b0, dinv, gA, N);

    f16* cur = gA;
    f16* nxt = gB;
    for (int l = 0; l < NSG; ++l) {
        int last = (l == NSG - 1) ? 1 : 0;
        float bscale = (float)(1u << l);             // s_l = 2^l
        sg_layer_kernel<<<(N + 63) / 64, 256, 0, stream>>>(
            cur, nxt, hF, rowptr, srcs, dinv,
            Wsall + (size_t)l * 32 * 32, bsall + (size_t)l * 32, N, bscale, last);
        f16* tmp = cur; cur = nxt; nxt = tmp;
    }

    linout_kernel<<<(N + 15) / 16, 256, 0, stream>>>(hF, W32, b32, (float*)d_out, N);
}